// Round 7
// baseline (602.757 us; speedup 1.0000x reference)
//
#include <hip/hip_runtime.h>
#include <hip/hip_bf16.h>

#define Nn 8192
#define Dd 512
#define KK 16
#define CC 32      // merged candidates per row (rescore input)
#define CSUB 8     // candidates kept per substream reservoir
#define TI 128
#define TJ 128
#define JSPLIT 32  // 32 J-chunks of 256 rows; 4 per XCD
#define JTILES 2   // 256 / TJ
#define NSUB (JSPLIT * 2)    // 64 substreams per row
#define PENT (NSUB * CSUB)   // 512 partial entries per row

typedef short bf16x8 __attribute__((ext_vector_type(8)));
typedef float f32x4 __attribute__((ext_vector_type(4)));
typedef unsigned int uint32;

__device__ __forceinline__ uint32 med3u(uint32 a, uint32 b, uint32 c) {
  uint32 d;
  asm("v_med3_u32 %0, %1, %2, %3" : "=v"(d) : "v"(a), "v"(b), "v"(c));
  return d;
}

// Branchless top-k (smallest keys) in a descending-sorted register array.
template <int CCn>
__device__ __forceinline__ void topk_insert(uint32* h, uint32 v) {
#pragma unroll
  for (int s = 0; s < CCn - 1; ++s) h[s] = med3u(h[s], h[s + 1], v);
  h[CCn - 1] = (h[CCn - 1] < v) ? h[CCn - 1] : v;
}

// ---- Barrier-free bitonic: compare-exchange with shfl partner (j <= 32) ----
__device__ __forceinline__ uint32 cswap(uint32 v, int j, bool asc, int lane) {
  uint32 pv = (uint32)__shfl_xor((int)v, j, 64);
  uint32 mn = v < pv ? v : pv;
  uint32 mx = v < pv ? pv : v;
  const bool lower = ((lane & j) == 0);
  return (asc == lower) ? mn : mx;
}

// Full ascending sort of 128 uint keys held 2-per-lane across one wave.
__device__ __forceinline__ void sort128(uint32& v0, uint32& v1, int lane) {
#pragma unroll
  for (int k = 2; k <= 32; k <<= 1) {
#pragma unroll
    for (int j = k >> 1; j > 0; j >>= 1) {
      const bool asc = ((lane & k) == 0);
      v0 = cswap(v0, j, asc, lane);
      v1 = cswap(v1, j, asc, lane);
    }
  }
#pragma unroll
  for (int j = 32; j > 0; j >>= 1) {
    v0 = cswap(v0, j, true, lane);
    v1 = cswap(v1, j, false, lane);
  }
  {
    uint32 mn = v0 < v1 ? v0 : v1;
    uint32 mx = v0 < v1 ? v1 : v0;
    v0 = mn;
    v1 = mx;
  }
#pragma unroll
  for (int j = 32; j > 0; j >>= 1) {
    v0 = cswap(v0, j, true, lane);
    v1 = cswap(v1, j, true, lane);
  }
}

__device__ __forceinline__ uint32 rne_pack(float a, float b) {
  uint32 ua = __builtin_bit_cast(uint32, a);
  uint32 ub = __builtin_bit_cast(uint32, b);
  uint32 ba = (ua + 0x7FFFu + ((ua >> 16) & 1u)) >> 16;
  uint32 bb = (ub + 0x7FFFu + ((ub >> 16) & 1u)) >> 16;
  return ba | (bb << 16);
}

// -------- Kernel A: fp32 -> bf16 in MFMA-fragment order + row sq-norms --------
// xbA frag layout: frag (rb, cc, r16) at index (rb*64+cc)*16 + r16 (16B each)
// holds row rb*16+r16, cols cc*8 .. cc*8+7.
__global__ void knn_prep(const float* __restrict__ x, uint4* __restrict__ xbA,
                         float* __restrict__ sq) {
  __shared__ float sqS[16][17];
  const int rb = blockIdx.x;  // 512 blocks, one 16-row block each
  const int t = threadIdx.x;
  const int ccg = t & 15;   // col-chunk group (coalesced reads)
  const int r16 = t >> 4;   // row within block
  const int row = rb * 16 + r16;
  float s = 0.f;
#pragma unroll
  for (int it = 0; it < 4; ++it) {
    const int cc = it * 16 + ccg;
    float4 a = *(const float4*)&x[(size_t)row * Dd + cc * 8];
    float4 b = *(const float4*)&x[(size_t)row * Dd + cc * 8 + 4];
    s = fmaf(a.x, a.x, s); s = fmaf(a.y, a.y, s);
    s = fmaf(a.z, a.z, s); s = fmaf(a.w, a.w, s);
    s = fmaf(b.x, b.x, s); s = fmaf(b.y, b.y, s);
    s = fmaf(b.z, b.z, s); s = fmaf(b.w, b.w, s);
    uint4 o;
    o.x = rne_pack(a.x, a.y);
    o.y = rne_pack(a.z, a.w);
    o.z = rne_pack(b.x, b.y);
    o.w = rne_pack(b.z, b.w);
    xbA[(size_t)(rb * 64 + cc) * 16 + r16] = o;
  }
  sqS[r16][ccg] = s;
  __syncthreads();
  if (t < 16) {
    float tot = 0.f;
#pragma unroll
    for (int i = 0; i < 16; ++i) tot += sqS[t][i];
    sq[rb * 16 + t] = tot;
  }
}

// ------- Kernel B: barrier-free MFMA K-loop (operands direct from L1/L2) -------
// 2-D XCD partition keeps A (2MB window) + B (1MB slice) L2-resident; fragment-
// ordered xbA makes every operand load one coalesced wave-wide 1KB dwordx4.
__global__ __launch_bounds__(256, 4) void knn_cand(
    const uint4* __restrict__ xbA, const float* __restrict__ sq,
    uint32* __restrict__ partials) {
  __shared__ float d2s[TI][32];  // 16 KB
  __shared__ float sqj[TJ];

  const int bid = blockIdx.x;
  const int xcd = bid & 7;
  const int jc = xcd * 4 + ((bid >> 3) & 3);  // [0,32)
  const int ib = bid >> 5;                    // [0,64)
  const int t = threadIdx.x;
  const int w = t >> 6;
  const int l = t & 63;
  const int wrow = w >> 1, wcol = w & 1;
  const int l16 = l & 15, lq = l >> 4;

  const int row_s = t >> 1;
  const int hv = t & 1;
  const int irow_g = ib * TI + row_s;

  const bf16x8* xf = (const bf16x8*)xbA;

  uint32 heap[CSUB];
#pragma unroll
  for (int s = 0; s < CSUB; ++s) heap[s] = 0xFFFFFFFFu;

  for (int jt = 0; jt < JTILES; ++jt) {
    const int jbase = jc * 256 + jt * TJ;
    const int abase = ib * 8 + wrow * 4;             // A rb base
    const int bbase = jc * 16 + jt * 8 + wcol * 4;   // B rb base

    f32x4 acc[4][4];
#pragma unroll
    for (int a = 0; a < 4; ++a)
#pragma unroll
      for (int b = 0; b < 4; ++b) acc[a][b] = (f32x4){0.f, 0.f, 0.f, 0.f};

#pragma unroll
    for (int kk = 0; kk < 8; ++kk) {
#pragma unroll
      for (int ks = 0; ks < 2; ++ks) {
        const int cc = kk * 8 + ks * 4 + lq;
        bf16x8 af[4], bfr[4];
#pragma unroll
        for (int fi = 0; fi < 4; ++fi)
          af[fi] = xf[((abase + fi) * 64 + cc) * 16 + l16];
#pragma unroll
        for (int fj = 0; fj < 4; ++fj)
          bfr[fj] = xf[((bbase + fj) * 64 + cc) * 16 + l16];
#pragma unroll
        for (int fi = 0; fi < 4; ++fi)
#pragma unroll
          for (int fj = 0; fj < 4; ++fj)
            acc[fi][fj] = __builtin_amdgcn_mfma_f32_16x16x32_bf16(
                af[fi], bfr[fj], acc[fi][fj], 0, 0, 0);
      }
    }

    __syncthreads();  // previous jt's scan reads of d2s/sqj complete
    if (t < TJ) sqj[t] = sq[jbase + t];

    // Four 32-col phases: stage dots to d2s (chunk-swizzled), scan.
#pragma unroll
    for (int p = 0; p < 4; ++p) {
      if (p > 0) __syncthreads();  // previous phase's scan reads done
      if (wcol == (p >> 1)) {
        const int fjp = p & 1;
#pragma unroll
        for (int fi = 0; fi < 4; ++fi)
#pragma unroll
          for (int fjh = 0; fjh < 2; ++fjh) {
            const int fj = fjp * 2 + fjh;
#pragma unroll
            for (int r = 0; r < 4; ++r) {
              const int row = wrow * 64 + fi * 16 + lq * 4 + r;
              const int c = fjh * 16 + l16;
              const int cs2 = (((c >> 2) ^ (row & 7)) << 2) | (c & 3);
              d2s[row][cs2] = acc[fi][fj][r];
            }
          }
      }
      __syncthreads();  // d2s writes (and sqj for p=0) visible
      const uint32 jg0 = (uint32)(jbase + p * 32 + hv * 16);
#pragma unroll
      for (int u2 = 0; u2 < 4; ++u2) {
        const int chunk = (hv * 4 + u2) ^ (row_s & 7);
        float4 v = *(const float4*)&d2s[row_s][chunk * 4];
        float vv[4] = {v.x, v.y, v.z, v.w};
#pragma unroll
        for (int e = 0; e < 4; ++e) {
          float key =
              fmaxf(fmaf(-2.f, vv[e], sqj[p * 32 + hv * 16 + u2 * 4 + e]), 0.f);
          uint32 packed = (__builtin_bit_cast(uint32, key) & 0xFFFFE000u) |
                          (jg0 + (uint32)(u2 * 4 + e));
          topk_insert<CSUB>(heap, packed);  // self removed later in rescore
        }
      }
    }
  }

  const int sub = jc * 2 + hv;  // [0,64)
#pragma unroll
  for (int s = 0; s < CSUB; ++s)
    partials[(size_t)irow_g * PENT + sub * CSUB + s] = heap[s];
}

// ---- Kernel C: shfl-bitonic merge -> fp64 rescore -> average (re-gather) ----
__global__ __launch_bounds__(256) void knn_rescore(
    const float* __restrict__ x, const uint32* __restrict__ partials,
    float* __restrict__ out) {
  __shared__ uint32 topS[128];
  __shared__ int candS[CC];
  __shared__ double d2S[CC];
  __shared__ int selS[KK];
  const int row = blockIdx.x;
  const int t = threadIdx.x, w = t >> 6, l = t & 63;

  // Phase 1: each wave sorts its 128 partial entries fully in registers.
  {
    const uint32* prow = partials + (size_t)row * PENT + w * 128;
    uint32 v0 = prow[l];
    uint32 v1 = prow[64 + l];
    if ((v0 & 0x1FFFu) == (uint32)row) v0 = 0xFFFFFFFFu;  // drop self
    if ((v1 & 0x1FFFu) == (uint32)row) v1 = 0xFFFFFFFFu;
    sort128(v0, v1, l);
    if (l < 32) topS[w * 32 + l] = v0;
  }
  __syncthreads();
  // Phase 2: wave 0 sorts the 4x32 survivors; first 32 = exact global top-32.
  if (w == 0) {
    uint32 u0 = topS[l], u1 = topS[64 + l];
    sort128(u0, u1, l);
    if (l < 32) candS[l] = (int)(u0 & 0x1FFFu);
  }
  __syncthreads();

  // Phase 3: exact fp64 rescore of the 32 candidates (8 per wave).
  const float4* x4 = (const float4*)x;
  float4 xi0 = x4[(size_t)row * 128 + l];
  float4 xi1 = x4[(size_t)row * 128 + 64 + l];
#pragma unroll
  for (int u = 0; u < 8; ++u) {
    const int c = w * 8 + u;
    const int j = candS[c];
    float4 b0 = x4[(size_t)j * 128 + l];
    float4 b1 = x4[(size_t)j * 128 + 64 + l];
    double s = 0.0;
    double d0 = (double)xi0.x - (double)b0.x;
    double d1 = (double)xi0.y - (double)b0.y;
    double d2 = (double)xi0.z - (double)b0.z;
    double d3 = (double)xi0.w - (double)b0.w;
    s = fma(d0, d0, s); s = fma(d1, d1, s); s = fma(d2, d2, s); s = fma(d3, d3, s);
    d0 = (double)xi1.x - (double)b1.x;
    d1 = (double)xi1.y - (double)b1.y;
    d2 = (double)xi1.z - (double)b1.z;
    d3 = (double)xi1.w - (double)b1.w;
    s = fma(d0, d0, s); s = fma(d1, d1, s); s = fma(d2, d2, s); s = fma(d3, d3, s);
#pragma unroll
    for (int off = 32; off > 0; off >>= 1) s += __shfl_down(s, off);
    if (l == 0) d2S[c] = s;
  }
  __syncthreads();
  // Phase 4: rank among 32 (ties broken by index, matching stable argsort).
  if (t < CC) {
    const double mine = d2S[t];
    const int mi = candS[t];
    int rank = 0;
#pragma unroll
    for (int o = 0; o < CC; ++o) {
      double vo = d2S[o];
      int io = candS[o];
      if (vo < mine || (vo == mine && io < mi)) rank++;
    }
    if (rank < KK) selS[rank] = mi;
  }
  __syncthreads();
  // Phase 5: average the 16 selected rows (coalesced re-gather, L2/L3-hot).
  const float2* x2 = (const float2*)x;
  float ax = 0.f, ay = 0.f;
#pragma unroll
  for (int n = 0; n < KK; ++n) {
    float2 vb = x2[(size_t)selS[n] * 256 + t];
    ax += vb.x;
    ay += vb.y;
  }
  ((float2*)out)[(size_t)row * 256 + t] = make_float2(ax * 0.0625f, ay * 0.0625f);
}

extern "C" void kernel_launch(void* const* d_in, const int* in_sizes, int n_in,
                              void* d_out, int out_size, void* d_ws,
                              size_t ws_size, hipStream_t stream) {
  const float* x = (const float*)d_in[0];
  float* out = (float*)d_out;
  char* ws = (char*)d_ws;
  // ws layout: xbA (8MB) | sq (32KB) | partials (16MB)  => 24.2 MB
  uint4* xbA = (uint4*)ws;
  float* sq = (float*)(ws + (size_t)Nn * Dd * 2);
  uint32* partials = (uint32*)(ws + (size_t)Nn * Dd * 2 + (size_t)Nn * 4);

  knn_prep<<<Nn / 16, 256, 0, stream>>>(x, xbA, sq);
  knn_cand<<<64 * JSPLIT, 256, 0, stream>>>(xbA, sq, partials);
  knn_rescore<<<Nn, 256, 0, stream>>>(x, partials, out);
}

// Round 8
// 336.321 us; speedup vs baseline: 1.7922x; 1.7922x over previous
//
#include <hip/hip_runtime.h>
#include <hip/hip_bf16.h>

#define Nn 8192
#define Dd 512
#define KK 16
#define CC 32      // merged candidates per row (rescore input)
#define CSUB 5     // per-lane reservoir size in knn_cand
#define JSPLIT 32  // 32 J-chunks of 256 rows; 4 per XCD
#define PENT 512   // partial entries per row (32 jc x 2 half x 8)

typedef short bf16x8 __attribute__((ext_vector_type(8)));
typedef float f32x4 __attribute__((ext_vector_type(4)));
typedef unsigned int uint32;

__device__ __forceinline__ uint32 med3u(uint32 a, uint32 b, uint32 c) {
  uint32 d;
  asm("v_med3_u32 %0, %1, %2, %3" : "=v"(d) : "v"(a), "v"(b), "v"(c));
  return d;
}

// Branchless top-k (smallest keys) in a descending-sorted register array.
template <int CCn>
__device__ __forceinline__ void topk_insert(uint32* h, uint32 v) {
#pragma unroll
  for (int s = 0; s < CCn - 1; ++s) h[s] = med3u(h[s], h[s + 1], v);
  h[CCn - 1] = (h[CCn - 1] < v) ? h[CCn - 1] : v;
}

// ---- Barrier-free bitonic: compare-exchange with shfl partner (j <= 32) ----
__device__ __forceinline__ uint32 cswap(uint32 v, int j, bool asc, int lane) {
  uint32 pv = (uint32)__shfl_xor((int)v, j, 64);
  uint32 mn = v < pv ? v : pv;
  uint32 mx = v < pv ? pv : v;
  const bool lower = ((lane & j) == 0);
  return (asc == lower) ? mn : mx;
}

// Full ascending sort of 128 uint keys held 2-per-lane across one wave.
__device__ __forceinline__ void sort128(uint32& v0, uint32& v1, int lane) {
#pragma unroll
  for (int k = 2; k <= 32; k <<= 1) {
#pragma unroll
    for (int j = k >> 1; j > 0; j >>= 1) {
      const bool asc = ((lane & k) == 0);
      v0 = cswap(v0, j, asc, lane);
      v1 = cswap(v1, j, asc, lane);
    }
  }
#pragma unroll
  for (int j = 32; j > 0; j >>= 1) {
    v0 = cswap(v0, j, true, lane);
    v1 = cswap(v1, j, false, lane);
  }
  {
    uint32 mn = v0 < v1 ? v0 : v1;
    uint32 mx = v0 < v1 ? v1 : v0;
    v0 = mn;
    v1 = mx;
  }
#pragma unroll
  for (int j = 32; j > 0; j >>= 1) {
    v0 = cswap(v0, j, true, lane);
    v1 = cswap(v1, j, true, lane);
  }
}

__device__ __forceinline__ uint32 rne_pack(float a, float b) {
  uint32 ua = __builtin_bit_cast(uint32, a);
  uint32 ub = __builtin_bit_cast(uint32, b);
  uint32 ba = (ua + 0x7FFFu + ((ua >> 16) & 1u)) >> 16;
  uint32 bb = (ub + 0x7FFFu + ((ub >> 16) & 1u)) >> 16;
  return ba | (bb << 16);
}

// -------- Kernel A: fp32 -> bf16 in MFMA-fragment order + row sq-norms --------
// xbA frag layout: frag (rb, cc, r16) at index (rb*64+cc)*16 + r16 (16B each)
// holds row rb*16+r16, cols cc*8 .. cc*8+7.
__global__ void knn_prep(const float* __restrict__ x, uint4* __restrict__ xbA,
                         float* __restrict__ sq) {
  __shared__ float sqS[16][17];
  const int rb = blockIdx.x;  // 512 blocks, one 16-row block each
  const int t = threadIdx.x;
  const int ccg = t & 15;   // col-chunk group (coalesced reads)
  const int r16 = t >> 4;   // row within block
  const int row = rb * 16 + r16;
  float s = 0.f;
#pragma unroll
  for (int it = 0; it < 4; ++it) {
    const int cc = it * 16 + ccg;
    float4 a = *(const float4*)&x[(size_t)row * Dd + cc * 8];
    float4 b = *(const float4*)&x[(size_t)row * Dd + cc * 8 + 4];
    s = fmaf(a.x, a.x, s); s = fmaf(a.y, a.y, s);
    s = fmaf(a.z, a.z, s); s = fmaf(a.w, a.w, s);
    s = fmaf(b.x, b.x, s); s = fmaf(b.y, b.y, s);
    s = fmaf(b.z, b.z, s); s = fmaf(b.w, b.w, s);
    uint4 o;
    o.x = rne_pack(a.x, a.y);
    o.y = rne_pack(a.z, a.w);
    o.z = rne_pack(b.x, b.y);
    o.w = rne_pack(b.z, b.w);
    xbA[(size_t)(rb * 64 + cc) * 16 + r16] = o;
  }
  sqS[r16][ccg] = s;
  __syncthreads();
  if (t < 16) {
    float tot = 0.f;
#pragma unroll
    for (int i = 0; i < 16; ++i) tot += sqS[t][i];
    sq[rb * 16 + t] = tot;
  }
}

// ------- Kernel B: barrier-free MFMA + in-register top-k (swapped operands) -------
// mfma(bfr, af) gives C^T: lane holds j = jbase + wcol*64 + fj*16 + lq*4 + r,
// i = ib*128 + wrow*64 + fi*16 + l16 -> selection over j runs on acc directly.
// No LDS staging at all; single barrier at end-of-kernel merge.
__global__ __launch_bounds__(256, 2) void knn_cand(
    const uint4* __restrict__ xbA, const float* __restrict__ sq,
    uint32* __restrict__ partials) {
  __shared__ uint32 entS[128][41];  // 21 KB: per-row 8 sources x 5 entries

  const int bid = blockIdx.x;
  const int xcd = bid & 7;
  const int jc = xcd * 4 + ((bid >> 3) & 3);  // [0,32)
  const int ib = bid >> 5;                    // [0,64)
  const int t = threadIdx.x;
  const int w = t >> 6;
  const int l = t & 63;
  const int wrow = w >> 1, wcol = w & 1;
  const int l16 = l & 15, lq = l >> 4;

  const bf16x8* xf = (const bf16x8*)xbA;
  const int abase = ib * 8 + wrow * 4;

  uint32 heap[4][CSUB];
#pragma unroll
  for (int fi = 0; fi < 4; ++fi)
#pragma unroll
    for (int s = 0; s < CSUB; ++s) heap[fi][s] = 0xFFFFFFFFu;

  for (int jt = 0; jt < 2; ++jt) {
    const int jbase = jc * 256 + jt * 128;
    const int bbase = jc * 16 + jt * 8 + wcol * 4;

    f32x4 acc[4][4];
#pragma unroll
    for (int a = 0; a < 4; ++a)
#pragma unroll
      for (int b = 0; b < 4; ++b) acc[a][b] = (f32x4){0.f, 0.f, 0.f, 0.f};

#pragma unroll
    for (int kk = 0; kk < 8; ++kk) {
#pragma unroll
      for (int ks = 0; ks < 2; ++ks) {
        const int cc = kk * 8 + ks * 4 + lq;
        bf16x8 af[4], bfr[4];
#pragma unroll
        for (int fi = 0; fi < 4; ++fi)
          af[fi] = xf[((abase + fi) * 64 + cc) * 16 + l16];
#pragma unroll
        for (int fj = 0; fj < 4; ++fj)
          bfr[fj] = xf[((bbase + fj) * 64 + cc) * 16 + l16];
#pragma unroll
        for (int fi = 0; fi < 4; ++fi)
#pragma unroll
          for (int fj = 0; fj < 4; ++fj)
            acc[fi][fj] = __builtin_amdgcn_mfma_f32_16x16x32_bf16(
                bfr[fj], af[fi], acc[fi][fj], 0, 0, 0);  // swapped: C^T
      }
    }

    // In-register selection: key = sq_j - 2*dot (row-constant dropped), >= 0.
    const uint32 jg_base = (uint32)(jbase + wcol * 64 + lq * 4);
#pragma unroll
    for (int fj = 0; fj < 4; ++fj) {
      const float4 s4 =
          *(const float4*)&sq[jbase + wcol * 64 + fj * 16 + lq * 4];
      const float sv[4] = {s4.x, s4.y, s4.z, s4.w};
#pragma unroll
      for (int r = 0; r < 4; ++r) {
        const uint32 jg = jg_base + (uint32)(fj * 16 + r);
#pragma unroll
        for (int fi = 0; fi < 4; ++fi) {
          float key = fmaxf(fmaf(-2.f, acc[fi][fj][r], sv[r]), 0.f);
          uint32 packed = (__builtin_bit_cast(uint32, key) & 0xFFFFE000u) | jg;
          topk_insert<CSUB>(heap[fi], packed);  // self removed in rescore
        }
      }
    }
  }

  // End-of-kernel merge: 8 lane-reservoirs per row -> top-8 per (row, half).
#pragma unroll
  for (int fi = 0; fi < 4; ++fi)
#pragma unroll
    for (int s = 0; s < CSUB; ++s)
      entS[wrow * 64 + fi * 16 + l16][(wcol * 4 + lq) * CSUB + s] =
          heap[fi][s];
  __syncthreads();

  const int row_s = t >> 1, half = t & 1;
  uint32 mh[8];
#pragma unroll
  for (int s = 0; s < 8; ++s) mh[s] = 0xFFFFFFFFu;
#pragma unroll
  for (int e = 0; e < 20; ++e)
    topk_insert<8>(mh, entS[row_s][half * 20 + e]);
  const int irow = ib * 128 + row_s;
#pragma unroll
  for (int s = 0; s < 8; ++s)
    partials[(size_t)irow * PENT + jc * 16 + half * 8 + s] = mh[s];
}

// ---- Kernel C: shfl-bitonic merge -> fp64 rescore -> average (re-gather) ----
__global__ __launch_bounds__(256) void knn_rescore(
    const float* __restrict__ x, const uint32* __restrict__ partials,
    float* __restrict__ out) {
  __shared__ uint32 topS[128];
  __shared__ int candS[CC];
  __shared__ double d2S[CC];
  __shared__ int selS[KK];
  const int row = blockIdx.x;
  const int t = threadIdx.x, w = t >> 6, l = t & 63;

  // Phase 1: each wave sorts its 128 partial entries fully in registers.
  {
    const uint32* prow = partials + (size_t)row * PENT + w * 128;
    uint32 v0 = prow[l];
    uint32 v1 = prow[64 + l];
    if ((v0 & 0x1FFFu) == (uint32)row) v0 = 0xFFFFFFFFu;  // drop self
    if ((v1 & 0x1FFFu) == (uint32)row) v1 = 0xFFFFFFFFu;
    sort128(v0, v1, l);
    if (l < 32) topS[w * 32 + l] = v0;
  }
  __syncthreads();
  // Phase 2: wave 0 sorts the 4x32 survivors; first 32 = exact global top-32.
  if (w == 0) {
    uint32 u0 = topS[l], u1 = topS[64 + l];
    sort128(u0, u1, l);
    if (l < 32) candS[l] = (int)(u0 & 0x1FFFu);
  }
  __syncthreads();

  // Phase 3: exact fp64 rescore of the 32 candidates (8 per wave).
  const float4* x4 = (const float4*)x;
  float4 xi0 = x4[(size_t)row * 128 + l];
  float4 xi1 = x4[(size_t)row * 128 + 64 + l];
#pragma unroll
  for (int u = 0; u < 8; ++u) {
    const int c = w * 8 + u;
    const int j = candS[c];
    float4 b0 = x4[(size_t)j * 128 + l];
    float4 b1 = x4[(size_t)j * 128 + 64 + l];
    double s = 0.0;
    double d0 = (double)xi0.x - (double)b0.x;
    double d1 = (double)xi0.y - (double)b0.y;
    double d2 = (double)xi0.z - (double)b0.z;
    double d3 = (double)xi0.w - (double)b0.w;
    s = fma(d0, d0, s); s = fma(d1, d1, s); s = fma(d2, d2, s); s = fma(d3, d3, s);
    d0 = (double)xi1.x - (double)b1.x;
    d1 = (double)xi1.y - (double)b1.y;
    d2 = (double)xi1.z - (double)b1.z;
    d3 = (double)xi1.w - (double)b1.w;
    s = fma(d0, d0, s); s = fma(d1, d1, s); s = fma(d2, d2, s); s = fma(d3, d3, s);
#pragma unroll
    for (int off = 32; off > 0; off >>= 1) s += __shfl_down(s, off);
    if (l == 0) d2S[c] = s;
  }
  __syncthreads();
  // Phase 4: rank among 32 (ties broken by index, matching stable argsort).
  if (t < CC) {
    const double mine = d2S[t];
    const int mi = candS[t];
    int rank = 0;
#pragma unroll
    for (int o = 0; o < CC; ++o) {
      double vo = d2S[o];
      int io = candS[o];
      if (vo < mine || (vo == mine && io < mi)) rank++;
    }
    if (rank < KK) selS[rank] = mi;
  }
  __syncthreads();
  // Phase 5: average the 16 selected rows (coalesced re-gather, L2/L3-hot).
  const float2* x2 = (const float2*)x;
  float ax = 0.f, ay = 0.f;
#pragma unroll
  for (int n = 0; n < KK; ++n) {
    float2 vb = x2[(size_t)selS[n] * 256 + t];
    ax += vb.x;
    ay += vb.y;
  }
  ((float2*)out)[(size_t)row * 256 + t] = make_float2(ax * 0.0625f, ay * 0.0625f);
}

extern "C" void kernel_launch(void* const* d_in, const int* in_sizes, int n_in,
                              void* d_out, int out_size, void* d_ws,
                              size_t ws_size, hipStream_t stream) {
  const float* x = (const float*)d_in[0];
  float* out = (float*)d_out;
  char* ws = (char*)d_ws;
  // ws layout: xbA (8MB) | sq (32KB) | partials (16MB)  => 24.2 MB
  uint4* xbA = (uint4*)ws;
  float* sq = (float*)(ws + (size_t)Nn * Dd * 2);
  uint32* partials = (uint32*)(ws + (size_t)Nn * Dd * 2 + (size_t)Nn * 4);

  knn_prep<<<Nn / 16, 256, 0, stream>>>(x, xbA, sq);
  knn_cand<<<64 * JSPLIT, 256, 0, stream>>>(xbA, sq, partials);
  knn_rescore<<<Nn, 256, 0, stream>>>(x, partials, out);
}

// Round 9
// 168.996 us; speedup vs baseline: 3.5667x; 1.9901x over previous
//
#include <hip/hip_runtime.h>
#include <hip/hip_bf16.h>

#define Nn 8192
#define Dd 512
#define KK 16
#define CC 32      // merged candidates per row (rescore input)
#define CSUB 5     // per-lane reservoir size in knn_cand
#define JSPLIT 32  // 32 J-chunks of 256 rows; 4 per XCD
#define PENT 512   // partial entries per row (32 jc x 2 half x 8)

typedef short bf16x8 __attribute__((ext_vector_type(8)));
typedef float f32x4 __attribute__((ext_vector_type(4)));
typedef unsigned int uint32;

__device__ __forceinline__ uint32 med3u(uint32 a, uint32 b, uint32 c) {
  uint32 d;
  asm("v_med3_u32 %0, %1, %2, %3" : "=v"(d) : "v"(a), "v"(b), "v"(c));
  return d;
}

// Branchless top-k (smallest keys) in a descending-sorted register array.
template <int CCn>
__device__ __forceinline__ void topk_insert(uint32* h, uint32 v) {
#pragma unroll
  for (int s = 0; s < CCn - 1; ++s) h[s] = med3u(h[s], h[s + 1], v);
  h[CCn - 1] = (h[CCn - 1] < v) ? h[CCn - 1] : v;
}

// ---- Barrier-free bitonic: compare-exchange with shfl partner (j <= 32) ----
__device__ __forceinline__ uint32 cswap(uint32 v, int j, bool asc, int lane) {
  uint32 pv = (uint32)__shfl_xor((int)v, j, 64);
  uint32 mn = v < pv ? v : pv;
  uint32 mx = v < pv ? pv : v;
  const bool lower = ((lane & j) == 0);
  return (asc == lower) ? mn : mx;
}

// Full ascending sort of 128 uint keys held 2-per-lane across one wave.
__device__ __forceinline__ void sort128(uint32& v0, uint32& v1, int lane) {
#pragma unroll
  for (int k = 2; k <= 32; k <<= 1) {
#pragma unroll
    for (int j = k >> 1; j > 0; j >>= 1) {
      const bool asc = ((lane & k) == 0);
      v0 = cswap(v0, j, asc, lane);
      v1 = cswap(v1, j, asc, lane);
    }
  }
#pragma unroll
  for (int j = 32; j > 0; j >>= 1) {
    v0 = cswap(v0, j, true, lane);
    v1 = cswap(v1, j, false, lane);
  }
  {
    uint32 mn = v0 < v1 ? v0 : v1;
    uint32 mx = v0 < v1 ? v1 : v0;
    v0 = mn;
    v1 = mx;
  }
#pragma unroll
  for (int j = 32; j > 0; j >>= 1) {
    v0 = cswap(v0, j, true, lane);
    v1 = cswap(v1, j, true, lane);
  }
}

__device__ __forceinline__ uint32 rne_pack(float a, float b) {
  uint32 ua = __builtin_bit_cast(uint32, a);
  uint32 ub = __builtin_bit_cast(uint32, b);
  uint32 ba = (ua + 0x7FFFu + ((ua >> 16) & 1u)) >> 16;
  uint32 bb = (ub + 0x7FFFu + ((ub >> 16) & 1u)) >> 16;
  return ba | (bb << 16);
}

// -------- Kernel A: fp32 -> bf16 in MFMA-fragment order + row sq-norms --------
// xbA frag layout: frag (rb, cc, r16) at index (rb*64+cc)*16 + r16 (16B each)
// holds row rb*16+r16, cols cc*8 .. cc*8+7.
__global__ void knn_prep(const float* __restrict__ x, uint4* __restrict__ xbA,
                         float* __restrict__ sq) {
  __shared__ float sqS[16][17];
  const int rb = blockIdx.x;  // 512 blocks, one 16-row block each
  const int t = threadIdx.x;
  const int ccg = t & 15;   // col-chunk group (coalesced reads)
  const int r16 = t >> 4;   // row within block
  const int row = rb * 16 + r16;
  float s = 0.f;
#pragma unroll
  for (int it = 0; it < 4; ++it) {
    const int cc = it * 16 + ccg;
    float4 a = *(const float4*)&x[(size_t)row * Dd + cc * 8];
    float4 b = *(const float4*)&x[(size_t)row * Dd + cc * 8 + 4];
    s = fmaf(a.x, a.x, s); s = fmaf(a.y, a.y, s);
    s = fmaf(a.z, a.z, s); s = fmaf(a.w, a.w, s);
    s = fmaf(b.x, b.x, s); s = fmaf(b.y, b.y, s);
    s = fmaf(b.z, b.z, s); s = fmaf(b.w, b.w, s);
    uint4 o;
    o.x = rne_pack(a.x, a.y);
    o.y = rne_pack(a.z, a.w);
    o.z = rne_pack(b.x, b.y);
    o.w = rne_pack(b.z, b.w);
    xbA[(size_t)(rb * 64 + cc) * 16 + r16] = o;
  }
  sqS[r16][ccg] = s;
  __syncthreads();
  if (t < 16) {
    float tot = 0.f;
#pragma unroll
    for (int i = 0; i < 16; ++i) tot += sqS[t][i];
    sq[rb * 16 + t] = tot;
  }
}

// ------- Kernel B: barrier-free MFMA + in-register top-k (swapped operands) -------
// mfma(bfr, af) gives C^T: lane holds j = jbase + wcol*64 + fj*16 + lq*4 + r.
// Register double-buffer (fa/fb, 8 frags each) with #pragma unroll 1 loops so
// the scheduler can never hoist more than one 8-load set (no spill).
__global__ __launch_bounds__(256, 2) void knn_cand(
    const uint4* __restrict__ xbA, const float* __restrict__ sq,
    uint32* __restrict__ partials) {
  __shared__ uint32 entS[128][41];  // 21 KB: per-row 8 sources x 5 entries

  const int bid = blockIdx.x;
  const int xcd = bid & 7;
  const int jc = xcd * 4 + ((bid >> 3) & 3);  // [0,32)
  const int ib = bid >> 5;                    // [0,64)
  const int t = threadIdx.x;
  const int w = t >> 6;
  const int l = t & 63;
  const int wrow = w >> 1, wcol = w & 1;
  const int l16 = l & 15, lq = l >> 4;

  const bf16x8* xf = (const bf16x8*)xbA;
  const int abase = ib * 8 + wrow * 4;

  uint32 heap[4][CSUB];
#pragma unroll
  for (int fi = 0; fi < 4; ++fi)
#pragma unroll
    for (int s = 0; s < CSUB; ++s) heap[fi][s] = 0xFFFFFFFFu;

#pragma unroll 1
  for (int jt = 0; jt < 2; ++jt) {
    const int jbase = jc * 256 + jt * 128;
    const int bbase = jc * 16 + jt * 8 + wcol * 4;
    // frag (q, kq): pX[q*1024 + kq*64]
    const bf16x8* pA = xf + ((size_t)(abase * 64 + lq) * 16 + l16);
    const bf16x8* pB = xf + ((size_t)(bbase * 64 + lq) * 16 + l16);

    f32x4 acc[4][4];
#pragma unroll
    for (int a = 0; a < 4; ++a)
#pragma unroll
      for (int b = 0; b < 4; ++b) acc[a][b] = (f32x4){0.f, 0.f, 0.f, 0.f};

    bf16x8 fa[8], fb[8];
#pragma unroll
    for (int q = 0; q < 4; ++q) {
      fa[q] = pA[q * 1024];
      fa[4 + q] = pB[q * 1024];
    }
#pragma unroll 1
    for (int kq = 0; kq < 16; kq += 2) {
#pragma unroll
      for (int q = 0; q < 4; ++q) {  // prefetch kq+1 into fb
        fb[q] = pA[q * 1024 + (kq + 1) * 64];
        fb[4 + q] = pB[q * 1024 + (kq + 1) * 64];
      }
#pragma unroll
      for (int fi = 0; fi < 4; ++fi)
#pragma unroll
        for (int fj = 0; fj < 4; ++fj)
          acc[fi][fj] = __builtin_amdgcn_mfma_f32_16x16x32_bf16(
              fa[4 + fj], fa[fi], acc[fi][fj], 0, 0, 0);  // swapped: C^T
      if (kq + 2 < 16) {
#pragma unroll
        for (int q = 0; q < 4; ++q) {  // prefetch kq+2 into fa
          fa[q] = pA[q * 1024 + (kq + 2) * 64];
          fa[4 + q] = pB[q * 1024 + (kq + 2) * 64];
        }
      }
#pragma unroll
      for (int fi = 0; fi < 4; ++fi)
#pragma unroll
        for (int fj = 0; fj < 4; ++fj)
          acc[fi][fj] = __builtin_amdgcn_mfma_f32_16x16x32_bf16(
              fb[4 + fj], fb[fi], acc[fi][fj], 0, 0, 0);
    }

    // In-register selection: key = sq_j - 2*dot (row-constant dropped), >= 0.
    const uint32 jg_base = (uint32)(jbase + wcol * 64 + lq * 4);
#pragma unroll
    for (int fj = 0; fj < 4; ++fj) {
      const float4 s4 =
          *(const float4*)&sq[jbase + wcol * 64 + fj * 16 + lq * 4];
      const float sv[4] = {s4.x, s4.y, s4.z, s4.w};
#pragma unroll
      for (int r = 0; r < 4; ++r) {
        const uint32 jg = jg_base + (uint32)(fj * 16 + r);
#pragma unroll
        for (int fi = 0; fi < 4; ++fi) {
          float key = fmaxf(fmaf(-2.f, acc[fi][fj][r], sv[r]), 0.f);
          uint32 packed = (__builtin_bit_cast(uint32, key) & 0xFFFFE000u) | jg;
          topk_insert<CSUB>(heap[fi], packed);  // self removed in rescore
        }
      }
    }
  }

  // End-of-kernel merge: 8 lane-reservoirs per row -> top-8 per (row, half).
#pragma unroll
  for (int fi = 0; fi < 4; ++fi)
#pragma unroll
    for (int s = 0; s < CSUB; ++s)
      entS[wrow * 64 + fi * 16 + l16][(wcol * 4 + lq) * CSUB + s] =
          heap[fi][s];
  __syncthreads();

  const int row_s = t >> 1, half = t & 1;
  uint32 mh[8];
#pragma unroll
  for (int s = 0; s < 8; ++s) mh[s] = 0xFFFFFFFFu;
#pragma unroll
  for (int e = 0; e < 20; ++e)
    topk_insert<8>(mh, entS[row_s][half * 20 + e]);
  const int irow = ib * 128 + row_s;
#pragma unroll
  for (int s = 0; s < 8; ++s)
    partials[(size_t)irow * PENT + jc * 16 + half * 8 + s] = mh[s];
}

// ---- Kernel C: shfl-bitonic merge -> fp64 rescore -> average (re-gather) ----
__global__ __launch_bounds__(256) void knn_rescore(
    const float* __restrict__ x, const uint32* __restrict__ partials,
    float* __restrict__ out) {
  __shared__ uint32 topS[128];
  __shared__ int candS[CC];
  __shared__ double d2S[CC];
  __shared__ int selS[KK];
  const int row = blockIdx.x;
  const int t = threadIdx.x, w = t >> 6, l = t & 63;

  // Phase 1: each wave sorts its 128 partial entries fully in registers.
  {
    const uint32* prow = partials + (size_t)row * PENT + w * 128;
    uint32 v0 = prow[l];
    uint32 v1 = prow[64 + l];
    if ((v0 & 0x1FFFu) == (uint32)row) v0 = 0xFFFFFFFFu;  // drop self
    if ((v1 & 0x1FFFu) == (uint32)row) v1 = 0xFFFFFFFFu;
    sort128(v0, v1, l);
    if (l < 32) topS[w * 32 + l] = v0;
  }
  __syncthreads();
  // Phase 2: wave 0 sorts the 4x32 survivors; first 32 = exact global top-32.
  if (w == 0) {
    uint32 u0 = topS[l], u1 = topS[64 + l];
    sort128(u0, u1, l);
    if (l < 32) candS[l] = (int)(u0 & 0x1FFFu);
  }
  __syncthreads();

  // Phase 3: exact fp64 rescore of the 32 candidates (8 per wave).
  const float4* x4 = (const float4*)x;
  float4 xi0 = x4[(size_t)row * 128 + l];
  float4 xi1 = x4[(size_t)row * 128 + 64 + l];
#pragma unroll
  for (int u = 0; u < 8; ++u) {
    const int c = w * 8 + u;
    const int j = candS[c];
    float4 b0 = x4[(size_t)j * 128 + l];
    float4 b1 = x4[(size_t)j * 128 + 64 + l];
    double s = 0.0;
    double d0 = (double)xi0.x - (double)b0.x;
    double d1 = (double)xi0.y - (double)b0.y;
    double d2 = (double)xi0.z - (double)b0.z;
    double d3 = (double)xi0.w - (double)b0.w;
    s = fma(d0, d0, s); s = fma(d1, d1, s); s = fma(d2, d2, s); s = fma(d3, d3, s);
    d0 = (double)xi1.x - (double)b1.x;
    d1 = (double)xi1.y - (double)b1.y;
    d2 = (double)xi1.z - (double)b1.z;
    d3 = (double)xi1.w - (double)b1.w;
    s = fma(d0, d0, s); s = fma(d1, d1, s); s = fma(d2, d2, s); s = fma(d3, d3, s);
#pragma unroll
    for (int off = 32; off > 0; off >>= 1) s += __shfl_down(s, off);
    if (l == 0) d2S[c] = s;
  }
  __syncthreads();
  // Phase 4: rank among 32 (ties broken by index, matching stable argsort).
  if (t < CC) {
    const double mine = d2S[t];
    const int mi = candS[t];
    int rank = 0;
#pragma unroll
    for (int o = 0; o < CC; ++o) {
      double vo = d2S[o];
      int io = candS[o];
      if (vo < mine || (vo == mine && io < mi)) rank++;
    }
    if (rank < KK) selS[rank] = mi;
  }
  __syncthreads();
  // Phase 5: average the 16 selected rows (coalesced re-gather, L2/L3-hot).
  const float2* x2 = (const float2*)x;
  float ax = 0.f, ay = 0.f;
#pragma unroll
  for (int n = 0; n < KK; ++n) {
    float2 vb = x2[(size_t)selS[n] * 256 + t];
    ax += vb.x;
    ay += vb.y;
  }
  ((float2*)out)[(size_t)row * 256 + t] = make_float2(ax * 0.0625f, ay * 0.0625f);
}

extern "C" void kernel_launch(void* const* d_in, const int* in_sizes, int n_in,
                              void* d_out, int out_size, void* d_ws,
                              size_t ws_size, hipStream_t stream) {
  const float* x = (const float*)d_in[0];
  float* out = (float*)d_out;
  char* ws = (char*)d_ws;
  // ws layout: xbA (8MB) | sq (32KB) | partials (16MB)  => 24.2 MB
  uint4* xbA = (uint4*)ws;
  float* sq = (float*)(ws + (size_t)Nn * Dd * 2);
  uint32* partials = (uint32*)(ws + (size_t)Nn * Dd * 2 + (size_t)Nn * 4);

  knn_prep<<<Nn / 16, 256, 0, stream>>>(x, xbA, sq);
  knn_cand<<<64 * JSPLIT, 256, 0, stream>>>(xbA, sq, partials);
  knn_rescore<<<Nn, 256, 0, stream>>>(x, partials, out);
}

// Round 10
// 158.204 us; speedup vs baseline: 3.8100x; 1.0682x over previous
//
#include <hip/hip_runtime.h>
#include <hip/hip_bf16.h>

#define Nn 8192
#define Dd 512
#define KK 16
#define CC 24      // merged candidates per row (rescore input)
#define CSUB 5     // per-lane reservoir size in knn_cand
#define JSPLIT 32  // 32 J-chunks of 256 rows; 4 per XCD
#define PENT 512   // partial entries per row (32 jc x 2 half x 8)

typedef short bf16x8 __attribute__((ext_vector_type(8)));
typedef float f32x4 __attribute__((ext_vector_type(4)));
typedef unsigned int uint32;

__device__ __forceinline__ uint32 med3u(uint32 a, uint32 b, uint32 c) {
  uint32 d;
  asm("v_med3_u32 %0, %1, %2, %3" : "=v"(d) : "v"(a), "v"(b), "v"(c));
  return d;
}

// Branchless top-k (smallest keys) in a descending-sorted register array.
template <int CCn>
__device__ __forceinline__ void topk_insert(uint32* h, uint32 v) {
#pragma unroll
  for (int s = 0; s < CCn - 1; ++s) h[s] = med3u(h[s], h[s + 1], v);
  h[CCn - 1] = (h[CCn - 1] < v) ? h[CCn - 1] : v;
}

// ---- Barrier-free bitonic: compare-exchange with shfl partner (j <= 32) ----
__device__ __forceinline__ uint32 cswap(uint32 v, int j, bool asc, int lane) {
  uint32 pv = (uint32)__shfl_xor((int)v, j, 64);
  uint32 mn = v < pv ? v : pv;
  uint32 mx = v < pv ? pv : v;
  const bool lower = ((lane & j) == 0);
  return (asc == lower) ? mn : mx;
}

// Full ascending sort of 128 uint keys held 2-per-lane across one wave.
__device__ __forceinline__ void sort128(uint32& v0, uint32& v1, int lane) {
#pragma unroll
  for (int k = 2; k <= 32; k <<= 1) {
#pragma unroll
    for (int j = k >> 1; j > 0; j >>= 1) {
      const bool asc = ((lane & k) == 0);
      v0 = cswap(v0, j, asc, lane);
      v1 = cswap(v1, j, asc, lane);
    }
  }
#pragma unroll
  for (int j = 32; j > 0; j >>= 1) {
    v0 = cswap(v0, j, true, lane);
    v1 = cswap(v1, j, false, lane);
  }
  {
    uint32 mn = v0 < v1 ? v0 : v1;
    uint32 mx = v0 < v1 ? v1 : v0;
    v0 = mn;
    v1 = mx;
  }
#pragma unroll
  for (int j = 32; j > 0; j >>= 1) {
    v0 = cswap(v0, j, true, lane);
    v1 = cswap(v1, j, true, lane);
  }
}

__device__ __forceinline__ uint32 rne_pack(float a, float b) {
  uint32 ua = __builtin_bit_cast(uint32, a);
  uint32 ub = __builtin_bit_cast(uint32, b);
  uint32 ba = (ua + 0x7FFFu + ((ua >> 16) & 1u)) >> 16;
  uint32 bb = (ub + 0x7FFFu + ((ub >> 16) & 1u)) >> 16;
  return ba | (bb << 16);
}

// -------- Kernel A: fp32 -> bf16 in MFMA-fragment order + row sq-norms --------
// xbA frag layout: frag (rb, cc, r16) at index (rb*64+cc)*16 + r16 (16B each)
// holds row rb*16+r16, cols cc*8 .. cc*8+7.
__global__ void knn_prep(const float* __restrict__ x, uint4* __restrict__ xbA,
                         float* __restrict__ sq) {
  __shared__ float sqS[16][17];
  const int rb = blockIdx.x;  // 512 blocks, one 16-row block each
  const int t = threadIdx.x;
  const int ccg = t & 15;   // col-chunk group (coalesced reads)
  const int r16 = t >> 4;   // row within block
  const int row = rb * 16 + r16;
  float s = 0.f;
#pragma unroll
  for (int it = 0; it < 4; ++it) {
    const int cc = it * 16 + ccg;
    float4 a = *(const float4*)&x[(size_t)row * Dd + cc * 8];
    float4 b = *(const float4*)&x[(size_t)row * Dd + cc * 8 + 4];
    s = fmaf(a.x, a.x, s); s = fmaf(a.y, a.y, s);
    s = fmaf(a.z, a.z, s); s = fmaf(a.w, a.w, s);
    s = fmaf(b.x, b.x, s); s = fmaf(b.y, b.y, s);
    s = fmaf(b.z, b.z, s); s = fmaf(b.w, b.w, s);
    uint4 o;
    o.x = rne_pack(a.x, a.y);
    o.y = rne_pack(a.z, a.w);
    o.z = rne_pack(b.x, b.y);
    o.w = rne_pack(b.z, b.w);
    xbA[(size_t)(rb * 64 + cc) * 16 + r16] = o;
  }
  sqS[r16][ccg] = s;
  __syncthreads();
  if (t < 16) {
    float tot = 0.f;
#pragma unroll
    for (int i = 0; i < 16; ++i) tot += sqS[t][i];
    sq[rb * 16 + t] = tot;
  }
}

// ------- Kernel B: barrier-free MFMA + in-register top-k (swapped operands) -------
// mfma(bfr, af) gives C^T: lane holds j = jbase + wcol*64 + fj*16 + lq*4 + r.
// Register double-buffer (fa/fb) with #pragma unroll 1 loops (no spill).
// launch_bounds(256,3): 12 waves/CU (regs ~152 <= 170 cap) for latency hiding.
__global__ __launch_bounds__(256, 3) void knn_cand(
    const uint4* __restrict__ xbA, const float* __restrict__ sq,
    uint32* __restrict__ partials) {
  __shared__ uint32 entS[128][41];  // 21 KB: per-row 8 sources x 5 entries

  const int bid = blockIdx.x;
  const int xcd = bid & 7;
  const int jc = xcd * 4 + ((bid >> 3) & 3);  // [0,32)
  const int ib = bid >> 5;                    // [0,64)
  const int t = threadIdx.x;
  const int w = t >> 6;
  const int l = t & 63;
  const int wrow = w >> 1, wcol = w & 1;
  const int l16 = l & 15, lq = l >> 4;

  const bf16x8* xf = (const bf16x8*)xbA;
  const int abase = ib * 8 + wrow * 4;

  uint32 heap[4][CSUB];
#pragma unroll
  for (int fi = 0; fi < 4; ++fi)
#pragma unroll
    for (int s = 0; s < CSUB; ++s) heap[fi][s] = 0xFFFFFFFFu;

#pragma unroll 1
  for (int jt = 0; jt < 2; ++jt) {
    const int jbase = jc * 256 + jt * 128;
    const int bbase = jc * 16 + jt * 8 + wcol * 4;
    // frag (q, kq): pX[q*1024 + kq*64]
    const bf16x8* pA = xf + ((size_t)(abase * 64 + lq) * 16 + l16);
    const bf16x8* pB = xf + ((size_t)(bbase * 64 + lq) * 16 + l16);

    f32x4 acc[4][4];
#pragma unroll
    for (int a = 0; a < 4; ++a)
#pragma unroll
      for (int b = 0; b < 4; ++b) acc[a][b] = (f32x4){0.f, 0.f, 0.f, 0.f};

    bf16x8 fa[8], fb[8];
#pragma unroll
    for (int q = 0; q < 4; ++q) {
      fa[q] = pA[q * 1024];
      fa[4 + q] = pB[q * 1024];
    }
#pragma unroll 1
    for (int kq = 0; kq < 16; kq += 2) {
#pragma unroll
      for (int q = 0; q < 4; ++q) {  // prefetch kq+1 into fb
        fb[q] = pA[q * 1024 + (kq + 1) * 64];
        fb[4 + q] = pB[q * 1024 + (kq + 1) * 64];
      }
      __builtin_amdgcn_s_setprio(1);
#pragma unroll
      for (int fi = 0; fi < 4; ++fi)
#pragma unroll
        for (int fj = 0; fj < 4; ++fj)
          acc[fi][fj] = __builtin_amdgcn_mfma_f32_16x16x32_bf16(
              fa[4 + fj], fa[fi], acc[fi][fj], 0, 0, 0);  // swapped: C^T
      __builtin_amdgcn_s_setprio(0);
      if (kq + 2 < 16) {
#pragma unroll
        for (int q = 0; q < 4; ++q) {  // prefetch kq+2 into fa
          fa[q] = pA[q * 1024 + (kq + 2) * 64];
          fa[4 + q] = pB[q * 1024 + (kq + 2) * 64];
        }
      }
      __builtin_amdgcn_s_setprio(1);
#pragma unroll
      for (int fi = 0; fi < 4; ++fi)
#pragma unroll
        for (int fj = 0; fj < 4; ++fj)
          acc[fi][fj] = __builtin_amdgcn_mfma_f32_16x16x32_bf16(
              fb[4 + fj], fb[fi], acc[fi][fj], 0, 0, 0);
      __builtin_amdgcn_s_setprio(0);
    }

    // In-register selection: key = sq_j - 2*dot (row-constant dropped), >= 0.
    const uint32 jg_base = (uint32)(jbase + wcol * 64 + lq * 4);
#pragma unroll
    for (int fj = 0; fj < 4; ++fj) {
      const float4 s4 =
          *(const float4*)&sq[jbase + wcol * 64 + fj * 16 + lq * 4];
      const float sv[4] = {s4.x, s4.y, s4.z, s4.w};
#pragma unroll
      for (int r = 0; r < 4; ++r) {
        const uint32 jg = jg_base + (uint32)(fj * 16 + r);
#pragma unroll
        for (int fi = 0; fi < 4; ++fi) {
          float key = fmaxf(fmaf(-2.f, acc[fi][fj][r], sv[r]), 0.f);
          uint32 packed = (__builtin_bit_cast(uint32, key) & 0xFFFFE000u) | jg;
          topk_insert<CSUB>(heap[fi], packed);  // self removed in rescore
        }
      }
    }
  }

  // End-of-kernel merge: 8 lane-reservoirs per row -> top-8 per (row, half).
#pragma unroll
  for (int fi = 0; fi < 4; ++fi)
#pragma unroll
    for (int s = 0; s < CSUB; ++s)
      entS[wrow * 64 + fi * 16 + l16][(wcol * 4 + lq) * CSUB + s] =
          heap[fi][s];
  __syncthreads();

  const int row_s = t >> 1, half = t & 1;
  uint32 mh[8];
#pragma unroll
  for (int s = 0; s < 8; ++s) mh[s] = 0xFFFFFFFFu;
#pragma unroll
  for (int e = 0; e < 20; ++e)
    topk_insert<8>(mh, entS[row_s][half * 20 + e]);
  const int irow = ib * 128 + row_s;
#pragma unroll
  for (int s = 0; s < 8; ++s)
    partials[(size_t)irow * PENT + jc * 16 + half * 8 + s] = mh[s];
}

// ---- Kernel C: shfl-bitonic merge -> fp64 rescore (top-24) -> average ----
__global__ __launch_bounds__(256) void knn_rescore(
    const float* __restrict__ x, const uint32* __restrict__ partials,
    float* __restrict__ out) {
  __shared__ uint32 topS[128];
  __shared__ int candS[CC];
  __shared__ double d2S[CC];
  __shared__ int selS[KK];
  const int row = blockIdx.x;
  const int t = threadIdx.x, w = t >> 6, l = t & 63;

  // Phase 1: each wave sorts its 128 partial entries fully in registers.
  {
    const uint32* prow = partials + (size_t)row * PENT + w * 128;
    uint32 v0 = prow[l];
    uint32 v1 = prow[64 + l];
    if ((v0 & 0x1FFFu) == (uint32)row) v0 = 0xFFFFFFFFu;  // drop self
    if ((v1 & 0x1FFFu) == (uint32)row) v1 = 0xFFFFFFFFu;
    sort128(v0, v1, l);
    if (l < 32) topS[w * 32 + l] = v0;
  }
  __syncthreads();
  // Phase 2: wave 0 sorts the 4x32 survivors; first CC = exact global top-CC.
  if (w == 0) {
    uint32 u0 = topS[l], u1 = topS[64 + l];
    sort128(u0, u1, l);
    if (l < CC) candS[l] = (int)(u0 & 0x1FFFu);
  }
  __syncthreads();

  // Phase 3: exact fp64 rescore of the 24 candidates (6 per wave).
  const float4* x4 = (const float4*)x;
  float4 xi0 = x4[(size_t)row * 128 + l];
  float4 xi1 = x4[(size_t)row * 128 + 64 + l];
#pragma unroll
  for (int u = 0; u < 6; ++u) {
    const int c = w * 6 + u;
    const int j = candS[c];
    float4 b0 = x4[(size_t)j * 128 + l];
    float4 b1 = x4[(size_t)j * 128 + 64 + l];
    double s = 0.0;
    double d0 = (double)xi0.x - (double)b0.x;
    double d1 = (double)xi0.y - (double)b0.y;
    double d2 = (double)xi0.z - (double)b0.z;
    double d3 = (double)xi0.w - (double)b0.w;
    s = fma(d0, d0, s); s = fma(d1, d1, s); s = fma(d2, d2, s); s = fma(d3, d3, s);
    d0 = (double)xi1.x - (double)b1.x;
    d1 = (double)xi1.y - (double)b1.y;
    d2 = (double)xi1.z - (double)b1.z;
    d3 = (double)xi1.w - (double)b1.w;
    s = fma(d0, d0, s); s = fma(d1, d1, s); s = fma(d2, d2, s); s = fma(d3, d3, s);
#pragma unroll
    for (int off = 32; off > 0; off >>= 1) s += __shfl_down(s, off);
    if (l == 0) d2S[c] = s;
  }
  __syncthreads();
  // Phase 4: rank among 24 (ties broken by index, matching stable argsort).
  if (t < CC) {
    const double mine = d2S[t];
    const int mi = candS[t];
    int rank = 0;
#pragma unroll
    for (int o = 0; o < CC; ++o) {
      double vo = d2S[o];
      int io = candS[o];
      if (vo < mine || (vo == mine && io < mi)) rank++;
    }
    if (rank < KK) selS[rank] = mi;
  }
  __syncthreads();
  // Phase 5: average the 16 selected rows (coalesced re-gather, L2/L3-hot).
  const float2* x2 = (const float2*)x;
  float ax = 0.f, ay = 0.f;
#pragma unroll
  for (int n = 0; n < KK; ++n) {
    float2 vb = x2[(size_t)selS[n] * 256 + t];
    ax += vb.x;
    ay += vb.y;
  }
  ((float2*)out)[(size_t)row * 256 + t] = make_float2(ax * 0.0625f, ay * 0.0625f);
}

extern "C" void kernel_launch(void* const* d_in, const int* in_sizes, int n_in,
                              void* d_out, int out_size, void* d_ws,
                              size_t ws_size, hipStream_t stream) {
  const float* x = (const float*)d_in[0];
  float* out = (float*)d_out;
  char* ws = (char*)d_ws;
  // ws layout: xbA (8MB) | sq (32KB) | partials (16MB)  => 24.2 MB
  uint4* xbA = (uint4*)ws;
  float* sq = (float*)(ws + (size_t)Nn * Dd * 2);
  uint32* partials = (uint32*)(ws + (size_t)Nn * Dd * 2 + (size_t)Nn * 4);

  knn_prep<<<Nn / 16, 256, 0, stream>>>(x, xbA, sq);
  knn_cand<<<64 * JSPLIT, 256, 0, stream>>>(xbA, sq, partials);
  knn_rescore<<<Nn, 256, 0, stream>>>(x, partials, out);
}

// Round 11
// 146.656 us; speedup vs baseline: 4.1100x; 1.0787x over previous
//
#include <hip/hip_runtime.h>
#include <hip/hip_bf16.h>

#define Nn 8192
#define Dd 512
#define KK 16
#define CC 24      // merged candidates per row (rescore input)
#define CSUB 5     // per-lane reservoir size in knn_cand
#define JSPLIT 32  // 32 J-chunks of 256 rows; 4 per XCD
#define PENT 512   // partial entries per row (32 jc x 2 half x 8)

typedef short bf16x8 __attribute__((ext_vector_type(8)));
typedef float f32x4 __attribute__((ext_vector_type(4)));
typedef unsigned int uint32;

__device__ __forceinline__ uint32 med3u(uint32 a, uint32 b, uint32 c) {
  uint32 d;
  asm("v_med3_u32 %0, %1, %2, %3" : "=v"(d) : "v"(a), "v"(b), "v"(c));
  return d;
}

// Branchless top-k (smallest keys) in a descending-sorted register array.
template <int CCn>
__device__ __forceinline__ void topk_insert(uint32* h, uint32 v) {
#pragma unroll
  for (int s = 0; s < CCn - 1; ++s) h[s] = med3u(h[s], h[s + 1], v);
  h[CCn - 1] = (h[CCn - 1] < v) ? h[CCn - 1] : v;
}

// ---- Barrier-free bitonic: compare-exchange with shfl partner (j <= 32) ----
__device__ __forceinline__ uint32 cswap(uint32 v, int j, bool asc, int lane) {
  uint32 pv = (uint32)__shfl_xor((int)v, j, 64);
  uint32 mn = v < pv ? v : pv;
  uint32 mx = v < pv ? pv : v;
  const bool lower = ((lane & j) == 0);
  return (asc == lower) ? mn : mx;
}

// Full ascending sort of 128 uint keys held 2-per-lane across one wave.
__device__ __forceinline__ void sort128(uint32& v0, uint32& v1, int lane) {
#pragma unroll
  for (int k = 2; k <= 32; k <<= 1) {
#pragma unroll
    for (int j = k >> 1; j > 0; j >>= 1) {
      const bool asc = ((lane & k) == 0);
      v0 = cswap(v0, j, asc, lane);
      v1 = cswap(v1, j, asc, lane);
    }
  }
#pragma unroll
  for (int j = 32; j > 0; j >>= 1) {
    v0 = cswap(v0, j, true, lane);
    v1 = cswap(v1, j, false, lane);
  }
  {
    uint32 mn = v0 < v1 ? v0 : v1;
    uint32 mx = v0 < v1 ? v1 : v0;
    v0 = mn;
    v1 = mx;
  }
#pragma unroll
  for (int j = 32; j > 0; j >>= 1) {
    v0 = cswap(v0, j, true, lane);
    v1 = cswap(v1, j, true, lane);
  }
}

__device__ __forceinline__ uint32 rne_pack(float a, float b) {
  uint32 ua = __builtin_bit_cast(uint32, a);
  uint32 ub = __builtin_bit_cast(uint32, b);
  uint32 ba = (ua + 0x7FFFu + ((ua >> 16) & 1u)) >> 16;
  uint32 bb = (ub + 0x7FFFu + ((ub >> 16) & 1u)) >> 16;
  return ba | (bb << 16);
}

// -------- Kernel A: fp32 -> bf16 in MFMA-fragment order + row sq-norms --------
// xbA frag layout: frag (rb, cc, r16) at index (rb*64+cc)*16 + r16 (16B each)
// holds row rb*16+r16, cols cc*8 .. cc*8+7.
__global__ void knn_prep(const float* __restrict__ x, uint4* __restrict__ xbA,
                         float* __restrict__ sq) {
  __shared__ float sqS[16][17];
  const int rb = blockIdx.x;  // 512 blocks, one 16-row block each
  const int t = threadIdx.x;
  const int ccg = t & 15;   // col-chunk group (coalesced reads)
  const int r16 = t >> 4;   // row within block
  const int row = rb * 16 + r16;
  float s = 0.f;
#pragma unroll
  for (int it = 0; it < 4; ++it) {
    const int cc = it * 16 + ccg;
    float4 a = *(const float4*)&x[(size_t)row * Dd + cc * 8];
    float4 b = *(const float4*)&x[(size_t)row * Dd + cc * 8 + 4];
    s = fmaf(a.x, a.x, s); s = fmaf(a.y, a.y, s);
    s = fmaf(a.z, a.z, s); s = fmaf(a.w, a.w, s);
    s = fmaf(b.x, b.x, s); s = fmaf(b.y, b.y, s);
    s = fmaf(b.z, b.z, s); s = fmaf(b.w, b.w, s);
    uint4 o;
    o.x = rne_pack(a.x, a.y);
    o.y = rne_pack(a.z, a.w);
    o.z = rne_pack(b.x, b.y);
    o.w = rne_pack(b.z, b.w);
    xbA[(size_t)(rb * 64 + cc) * 16 + r16] = o;
  }
  sqS[r16][ccg] = s;
  __syncthreads();
  if (t < 16) {
    float tot = 0.f;
#pragma unroll
    for (int i = 0; i < 16; ++i) tot += sqS[t][i];
    sq[rb * 16 + t] = tot;
  }
}

// ------- Kernel B: barrier-free MFMA, 64x128 wave tile (4x8 frags) -------
// Block tile 128x256 = full J-chunk (no jt loop). Intensity 21.3 MACs/B:
// register-load traffic 4GB -> 1.6GB vs the 64x64 tile. mfma(bfr, af) = C^T:
// lane holds j = jbase + wcol*128 + fj*16 + lq*4 + r, i-col = l16.
__global__ __launch_bounds__(256, 2) void knn_cand(
    const uint4* __restrict__ xbA, const float* __restrict__ sq,
    uint32* __restrict__ partials) {
  __shared__ uint32 entS[128][41];  // 21 KB: per-row 8 sources x 5 entries

  const int bid = blockIdx.x;
  const int xcd = bid & 7;
  const int jc = xcd * 4 + ((bid >> 3) & 3);  // [0,32)
  const int ib = bid >> 5;                    // [0,64)
  const int t = threadIdx.x;
  const int w = t >> 6;
  const int l = t & 63;
  const int wrow = w >> 1, wcol = w & 1;
  const int l16 = l & 15, lq = l >> 4;

  const bf16x8* xf = (const bf16x8*)xbA;
  const int abase = ib * 8 + wrow * 4;
  const int bbase = jc * 16 + wcol * 8;  // 8 rb-blocks = 128 j-rows
  const int jbase = jc * 256;

  // frag (q, kq): pX[q*1024 + kq*64]
  const bf16x8* pA = xf + ((size_t)(abase * 64 + lq) * 16 + l16);
  const bf16x8* pB = xf + ((size_t)(bbase * 64 + lq) * 16 + l16);

  uint32 heap[4][CSUB];
#pragma unroll
  for (int fi = 0; fi < 4; ++fi)
#pragma unroll
    for (int s = 0; s < CSUB; ++s) heap[fi][s] = 0xFFFFFFFFu;

  f32x4 acc[4][8];
#pragma unroll
  for (int a = 0; a < 4; ++a)
#pragma unroll
    for (int b = 0; b < 8; ++b) acc[a][b] = (f32x4){0.f, 0.f, 0.f, 0.f};

  bf16x8 fa0[4], fb0[8], fa1[4], fb1[8];
#pragma unroll
  for (int q = 0; q < 4; ++q) fa0[q] = pA[q * 1024];
#pragma unroll
  for (int q = 0; q < 8; ++q) fb0[q] = pB[q * 1024];

#pragma unroll 1
  for (int kq = 0; kq < 16; kq += 2) {
#pragma unroll
    for (int q = 0; q < 4; ++q) fa1[q] = pA[q * 1024 + (kq + 1) * 64];
#pragma unroll
    for (int q = 0; q < 8; ++q) fb1[q] = pB[q * 1024 + (kq + 1) * 64];
    __builtin_amdgcn_s_setprio(1);
#pragma unroll
    for (int fi = 0; fi < 4; ++fi)
#pragma unroll
      for (int fj = 0; fj < 8; ++fj)
        acc[fi][fj] = __builtin_amdgcn_mfma_f32_16x16x32_bf16(
            fb0[fj], fa0[fi], acc[fi][fj], 0, 0, 0);  // swapped: C^T
    __builtin_amdgcn_s_setprio(0);
    if (kq + 2 < 16) {
#pragma unroll
      for (int q = 0; q < 4; ++q) fa0[q] = pA[q * 1024 + (kq + 2) * 64];
#pragma unroll
      for (int q = 0; q < 8; ++q) fb0[q] = pB[q * 1024 + (kq + 2) * 64];
    }
    __builtin_amdgcn_s_setprio(1);
#pragma unroll
    for (int fi = 0; fi < 4; ++fi)
#pragma unroll
      for (int fj = 0; fj < 8; ++fj)
        acc[fi][fj] = __builtin_amdgcn_mfma_f32_16x16x32_bf16(
            fb1[fj], fa1[fi], acc[fi][fj], 0, 0, 0);
    __builtin_amdgcn_s_setprio(0);
  }

  // In-register selection: key = sq_j - 2*dot (row-constant dropped), >= 0.
  const uint32 jg_base = (uint32)(jbase + wcol * 128 + lq * 4);
#pragma unroll
  for (int fj = 0; fj < 8; ++fj) {
    const float4 s4 =
        *(const float4*)&sq[jbase + wcol * 128 + fj * 16 + lq * 4];
    const float sv[4] = {s4.x, s4.y, s4.z, s4.w};
#pragma unroll
    for (int r = 0; r < 4; ++r) {
      const uint32 jg = jg_base + (uint32)(fj * 16 + r);
#pragma unroll
      for (int fi = 0; fi < 4; ++fi) {
        float key = fmaxf(fmaf(-2.f, acc[fi][fj][r], sv[r]), 0.f);
        uint32 packed = (__builtin_bit_cast(uint32, key) & 0xFFFFE000u) | jg;
        topk_insert<CSUB>(heap[fi], packed);  // self removed in rescore
      }
    }
  }

  // End-of-kernel merge: 8 lane-reservoirs per row -> top-8 per (row, half).
#pragma unroll
  for (int fi = 0; fi < 4; ++fi)
#pragma unroll
    for (int s = 0; s < CSUB; ++s)
      entS[wrow * 64 + fi * 16 + l16][(wcol * 4 + lq) * CSUB + s] =
          heap[fi][s];
  __syncthreads();

  const int row_s = t >> 1, half = t & 1;
  uint32 mh[8];
#pragma unroll
  for (int s = 0; s < 8; ++s) mh[s] = 0xFFFFFFFFu;
#pragma unroll
  for (int e = 0; e < 20; ++e)
    topk_insert<8>(mh, entS[row_s][half * 20 + e]);
  const int irow = ib * 128 + row_s;
#pragma unroll
  for (int s = 0; s < 8; ++s)
    partials[(size_t)irow * PENT + jc * 16 + half * 8 + s] = mh[s];
}

// ---- Kernel C: shfl-bitonic merge -> fp64 rescore (top-24) -> average ----
__global__ __launch_bounds__(256) void knn_rescore(
    const float* __restrict__ x, const uint32* __restrict__ partials,
    float* __restrict__ out) {
  __shared__ uint32 topS[128];
  __shared__ int candS[CC];
  __shared__ double d2S[CC];
  __shared__ int selS[KK];
  const int row = blockIdx.x;
  const int t = threadIdx.x, w = t >> 6, l = t & 63;

  // Phase 1: each wave sorts its 128 partial entries fully in registers.
  {
    const uint32* prow = partials + (size_t)row * PENT + w * 128;
    uint32 v0 = prow[l];
    uint32 v1 = prow[64 + l];
    if ((v0 & 0x1FFFu) == (uint32)row) v0 = 0xFFFFFFFFu;  // drop self
    if ((v1 & 0x1FFFu) == (uint32)row) v1 = 0xFFFFFFFFu;
    sort128(v0, v1, l);
    if (l < 32) topS[w * 32 + l] = v0;
  }
  __syncthreads();
  // Phase 2: wave 0 sorts the 4x32 survivors; first CC = exact global top-CC.
  if (w == 0) {
    uint32 u0 = topS[l], u1 = topS[64 + l];
    sort128(u0, u1, l);
    if (l < CC) candS[l] = (int)(u0 & 0x1FFFu);
  }
  __syncthreads();

  // Phase 3: exact fp64 rescore of the 24 candidates (6 per wave).
  const float4* x4 = (const float4*)x;
  float4 xi0 = x4[(size_t)row * 128 + l];
  float4 xi1 = x4[(size_t)row * 128 + 64 + l];
#pragma unroll
  for (int u = 0; u < 6; ++u) {
    const int c = w * 6 + u;
    const int j = candS[c];
    float4 b0 = x4[(size_t)j * 128 + l];
    float4 b1 = x4[(size_t)j * 128 + 64 + l];
    double s = 0.0;
    double d0 = (double)xi0.x - (double)b0.x;
    double d1 = (double)xi0.y - (double)b0.y;
    double d2 = (double)xi0.z - (double)b0.z;
    double d3 = (double)xi0.w - (double)b0.w;
    s = fma(d0, d0, s); s = fma(d1, d1, s); s = fma(d2, d2, s); s = fma(d3, d3, s);
    d0 = (double)xi1.x - (double)b1.x;
    d1 = (double)xi1.y - (double)b1.y;
    d2 = (double)xi1.z - (double)b1.z;
    d3 = (double)xi1.w - (double)b1.w;
    s = fma(d0, d0, s); s = fma(d1, d1, s); s = fma(d2, d2, s); s = fma(d3, d3, s);
#pragma unroll
    for (int off = 32; off > 0; off >>= 1) s += __shfl_down(s, off);
    if (l == 0) d2S[c] = s;
  }
  __syncthreads();
  // Phase 4: rank among 24 (ties broken by index, matching stable argsort).
  if (t < CC) {
    const double mine = d2S[t];
    const int mi = candS[t];
    int rank = 0;
#pragma unroll
    for (int o = 0; o < CC; ++o) {
      double vo = d2S[o];
      int io = candS[o];
      if (vo < mine || (vo == mine && io < mi)) rank++;
    }
    if (rank < KK) selS[rank] = mi;
  }
  __syncthreads();
  // Phase 5: average the 16 selected rows (coalesced re-gather, L2/L3-hot).
  const float2* x2 = (const float2*)x;
  float ax = 0.f, ay = 0.f;
#pragma unroll
  for (int n = 0; n < KK; ++n) {
    float2 vb = x2[(size_t)selS[n] * 256 + t];
    ax += vb.x;
    ay += vb.y;
  }
  ((float2*)out)[(size_t)row * 256 + t] = make_float2(ax * 0.0625f, ay * 0.0625f);
}

extern "C" void kernel_launch(void* const* d_in, const int* in_sizes, int n_in,
                              void* d_out, int out_size, void* d_ws,
                              size_t ws_size, hipStream_t stream) {
  const float* x = (const float*)d_in[0];
  float* out = (float*)d_out;
  char* ws = (char*)d_ws;
  // ws layout: xbA (8MB) | sq (32KB) | partials (16MB)  => 24.2 MB
  uint4* xbA = (uint4*)ws;
  float* sq = (float*)(ws + (size_t)Nn * Dd * 2);
  uint32* partials = (uint32*)(ws + (size_t)Nn * Dd * 2 + (size_t)Nn * 4);

  knn_prep<<<Nn / 16, 256, 0, stream>>>(x, xbA, sq);
  knn_cand<<<64 * JSPLIT, 256, 0, stream>>>(xbA, sq, partials);
  knn_rescore<<<Nn, 256, 0, stream>>>(x, partials, out);
}